// Round 4
// baseline (1032.325 us; speedup 1.0000x reference)
//
#include <hip/hip_runtime.h>

#define NB 4096
#define NT 512
#define NI 25
#define NH 20
#define NL 10
#define CH 32

typedef float f4 __attribute__((ext_vector_type(4)));

#if __has_builtin(__builtin_amdgcn_rcpf)
__device__ __forceinline__ float rcpf(float x){ return __builtin_amdgcn_rcpf(x); }
#else
__device__ __forceinline__ float rcpf(float x){ return 1.0f/x; }
#endif

struct Smem {
  float xbuf[2][CH][32];  // 8 KB, padded stride 32 -> aligned b128 reads
  float hbuf[2][32];      // h (20) + zero pad to 32
  float gbuf[2][128];     // gates, lane k owns slots k*8..k*8+4
  float zbuf[2][12];
};

// p==0 lanes: x-part weights (25/gate) + bias; p==1 lanes: h-part (20/gate, pad 0)
__device__ __forceinline__ void load_weights(
    const float* __restrict__ Wih, const float* __restrict__ Whh,
    const float* __restrict__ bih, const float* __restrict__ bhh,
    int p, int k, float (&w)[5][25], float (&bias)[5])
{
#pragma unroll
  for (int g=0; g<5; ++g){
    const int G = 5*k+g;
    if (p==0){
#pragma unroll
      for (int i=0;i<25;++i) w[g][i] = Wih[G*25+i];
      bias[g] = bih[G] + bhh[G];
    } else {
#pragma unroll
      for (int j=0;j<20;++j) w[g][j] = Whh[G*20+j];
#pragma unroll
      for (int j=20;j<25;++j) w[g][j] = 0.f;
      bias[g] = 0.f;
    }
  }
}

template<bool DEC>
__device__ __forceinline__ void lstm_loop(
    const float* __restrict__ xblk,   // x + (blockIdx.x*2)*NT*NI
    Smem* sm, int lane, int r, int p, int k,
    const float (&w)[5][25], const float (&bias)[5],
    float& c,
    const float (&ow)[20], float obias,
    float* __restrict__ xhat)         // out + b*NT*NI + q2 on proj lanes
{
  const bool is_g = ((k>>2)==2);
  const float gmul = is_g ? -2.0f : -1.0f;
  const bool upd = (p==0) || (k<4);
  const int  m   = (p==0) ? k : 16+k;           // unit index (valid when upd)
  const int  ai  = (m/5)*8 + (m%5);             // gbuf addr of i-gate for unit m
  const int  q2  = lane & 31;
  const bool pj  = (q2 < 25);
  const float* opbase = (p==0) ? &sm->xbuf[r][0][0] : &sm->hbuf[r][0];

  for (int t=0; t<NT; ++t){
    const int tc = t & (CH-1);
    if (tc == 0){
      __syncthreads();
      // stage x chunk [t, t+CH) for both rows: 1600 floats, 25 per lane, coalesced
      const float* gsrc = xblk + (size_t)t*NI;
#pragma unroll
      for (int it=0; it<25; ++it){
        int idx = lane + it*64;            // 0..1599
        int rr  = (idx >= 800) ? 1 : 0;
        int o   = idx - rr*800;
        int tt  = o / 25;
        int ii  = o - tt*25;
        sm->xbuf[rr][tt][ii] = gsrc[(size_t)rr*NT*NI + (size_t)tt*NI + ii];
      }
      __syncthreads();
    }

    // operand slice: p0 -> x[t][0..24], p1 -> h[0..19] (pad zeros)
    const float* obp = (p==0) ? (opbase + tc*32) : opbase;
    float op[28];
#pragma unroll
    for (int v=0; v<7; ++v){
      f4 q = *(const f4*)(obp + 4*v);
      op[4*v+0]=q.x; op[4*v+1]=q.y; op[4*v+2]=q.z; op[4*v+3]=q.w;
    }

    float acc[5];
#pragma unroll
    for (int g=0; g<5; ++g) acc[g] = (p==0) ? bias[g] : 0.f;
#pragma unroll
    for (int i=0;i<25;++i){
      const float xv = op[i];
#pragma unroll
      for (int g=0;g<5;++g) acc[g] = fmaf(w[g][i], xv, acc[g]);
    }
    // combine x-part and h-part across the p axis (lane ^ 16)
#pragma unroll
    for (int g=0; g<5; ++g) acc[g] += __shfl_xor(acc[g], 16);

    float val[5];
#pragma unroll
    for (int g=0; g<5; ++g){
      float e = __expf(gmul*acc[g]);
      float s = rcpf(1.0f + e);
      val[g] = is_g ? (2.0f*s - 1.0f) : s;
    }
    if (p==0){
      f4 v4; v4.x=val[0]; v4.y=val[1]; v4.z=val[2]; v4.w=val[3];
      *(f4*)&sm->gbuf[r][k*8] = v4;
      sm->gbuf[r][k*8+4] = val[4];
    }
    __syncthreads();

    if (upd){
      float ig = sm->gbuf[r][ai];
      float fg = sm->gbuf[r][ai+32];
      float gg = sm->gbuf[r][ai+64];
      float og = sm->gbuf[r][ai+96];
      float cn = fmaf(fg, c, ig*gg);
      c = cn;
      float e  = __expf(-2.0f*cn);
      float th = 2.0f*rcpf(1.0f + e) - 1.0f;   // NaN-safe tanh
      sm->hbuf[r][m] = og*th;
    }
    __syncthreads();

    if (DEC && pj){
      float h[20];
#pragma unroll
      for (int v=0; v<5; ++v){
        f4 q = *(const f4*)(&sm->hbuf[r][4*v]);
        h[4*v+0]=q.x; h[4*v+1]=q.y; h[4*v+2]=q.z; h[4*v+3]=q.w;
      }
      float a = obias;
#pragma unroll
      for (int j=0;j<20;++j) a = fmaf(ow[j], h[j], a);
      xhat[(size_t)t*NI] = a;
    }
  }
}

__global__ __launch_bounds__(64,2) void lstm_vae_kernel(
  const float* __restrict__ x, const float* __restrict__ h0, const float* __restrict__ c0,
  const float* __restrict__ noise,
  const float* __restrict__ eWih, const float* __restrict__ eWhh, const float* __restrict__ ebih, const float* __restrict__ ebhh,
  const float* __restrict__ dWih, const float* __restrict__ dWhh, const float* __restrict__ dbih, const float* __restrict__ dbhh,
  const float* __restrict__ mW, const float* __restrict__ mb,
  const float* __restrict__ lW, const float* __restrict__ lb,
  const float* __restrict__ iW, const float* __restrict__ ib,
  const float* __restrict__ oW, const float* __restrict__ ob,
  float* __restrict__ out)
{
  __shared__ Smem sm;
  const int lane = threadIdx.x;
  const int r = lane>>5, p = (lane>>4)&1, k = lane&15;
  const int b = blockIdx.x*2 + r;
  const bool upd = (p==0) || (k<4);
  const int  m   = (p==0) ? k : 16+k;
  const float* xblk = x + (size_t)(blockIdx.x*2)*NT*NI;

  // zero hbuf (incl. pad) then set h0
  ((float*)sm.hbuf)[lane] = 0.f;
  float c = 0.f;
  __syncthreads();
  if (upd){
    sm.hbuf[r][m] = h0[(size_t)b*NH + m];
    c = c0[(size_t)b*NH + m];
  }

  float w[5][25], bias[5];
  load_weights(eWih, eWhh, ebih, ebhh, p, k, w, bias);
  float ow[20]; float obias = 0.f;
#pragma unroll
  for (int j=0;j<20;++j) ow[j] = 0.f;
  __syncthreads();

  lstm_loop<false>(xblk, &sm, lane, r, p, k, w, bias, c, ow, obias, nullptr);
  __syncthreads();

  const size_t OFF1 = (size_t)NB*NT*NI;
  const size_t OFF2 = OFF1 + (size_t)NB*NL;
  const size_t OFF3 = OFF2 + (size_t)NB*NL;
  const size_t OFF4 = OFF3 + (size_t)NB*NL;
  const size_t OFF5 = OFF4 + (size_t)NB*NH;

  if (upd){
    out[OFF4 + (size_t)b*NH + m] = sm.hbuf[r][m];
    out[OFF5 + (size_t)b*NH + m] = c;
  }

  if (p==0 && k<10){
    float h[20];
#pragma unroll
    for (int j=0;j<20;++j) h[j] = sm.hbuf[r][j];
    float mm = mb[k], lv = lb[k];
#pragma unroll
    for (int j=0;j<20;++j){
      mm = fmaf(mW[k*20+j], h[j], mm);
      lv = fmaf(lW[k*20+j], h[j], lv);
    }
    float sd = __expf(0.5f*lv);
    float zz = fmaf(noise[(size_t)b*NL + k], sd, mm);
    out[OFF1 + (size_t)b*NL + k] = mm;
    out[OFF2 + (size_t)b*NL + k] = lv;
    out[OFF3 + (size_t)b*NL + k] = zz;
    sm.zbuf[r][k] = zz;
  }
  __syncthreads();

  if (upd){
    float hd = ib[m];
#pragma unroll
    for (int l=0;l<10;++l) hd = fmaf(iW[m*10+l], sm.zbuf[r][l], hd);
    c = hd;
    sm.hbuf[r][m] = hd;
  }

  load_weights(dWih, dWhh, dbih, dbhh, p, k, w, bias);
  const int q2 = lane & 31;
  if (q2 < 25){
#pragma unroll
    for (int j=0;j<20;++j) ow[j] = oW[q2*20+j];
    obias = ob[q2];
  }
  float* xhat = out + (size_t)b*NT*NI + q2;
  __syncthreads();

  lstm_loop<true>(xblk, &sm, lane, r, p, k, w, bias, c, ow, obias, xhat);
}

extern "C" void kernel_launch(void* const* d_in, const int* in_sizes, int n_in,
                              void* d_out, int out_size, void* d_ws, size_t ws_size,
                              hipStream_t stream) {
  const float* x     = (const float*)d_in[0];
  const float* h0    = (const float*)d_in[1];
  const float* c0    = (const float*)d_in[2];
  const float* noise = (const float*)d_in[3];
  const float* eWih  = (const float*)d_in[4];
  const float* eWhh  = (const float*)d_in[5];
  const float* ebih  = (const float*)d_in[6];
  const float* ebhh  = (const float*)d_in[7];
  const float* dWih  = (const float*)d_in[8];
  const float* dWhh  = (const float*)d_in[9];
  const float* dbih  = (const float*)d_in[10];
  const float* dbhh  = (const float*)d_in[11];
  const float* mW    = (const float*)d_in[12];
  const float* mb    = (const float*)d_in[13];
  const float* lW    = (const float*)d_in[14];
  const float* lb    = (const float*)d_in[15];
  const float* iW    = (const float*)d_in[16];
  const float* ib    = (const float*)d_in[17];
  const float* oW    = (const float*)d_in[18];
  const float* ob    = (const float*)d_in[19];
  float* out = (float*)d_out;

  hipLaunchKernelGGL(lstm_vae_kernel, dim3(NB/2), dim3(64), 0, stream,
                     x, h0, c0, noise,
                     eWih, eWhh, ebih, ebhh,
                     dWih, dWhh, dbih, dbhh,
                     mW, mb, lW, lb, iW, ib, oW, ob, out);
}